// Round 2
// baseline (2227.378 us; speedup 1.0000x reference)
//
#include <hip/hip_runtime.h>
#include <stdint.h>

// ---------------------------------------------------------------------------
// Fused gated-equivariant dipole head, MI355X (gfx950).
// Inputs/outputs are FLOAT32 (per reference); GEMMs run in bf16 MFMA with
// fp32 accumulation (tolerance = 2% of max |ref| = 0.18, bf16 error ~0.03).
// One WG = 32 atoms, 512 threads (8 waves). All intermediates in LDS/regs.
// Phases: P1 vV GEMM -> vVn ; P2a/P2b MLP-a ; P3 vW GEMM fused with
// gate*Wmix2 contraction ; P4 MLP-b layer1 (K=257 folded to bias) ; P5 final
// dots + segment atomics into d_out (f32). Weights pre-transposed to bf16 in
// ws by a setup kernel (runs every launch; ws is re-poisoned each replay).
// ---------------------------------------------------------------------------

typedef float f32x4 __attribute__((ext_vector_type(4)));
typedef __bf16 bfrag8 __attribute__((ext_vector_type(8)));   // MFMA A/B operand (4 VGPRs)

#define N_ATOMS   200000
#define M_TILE    32
#define NWG       (N_ATOMS / M_TILE)   // 6250 exactly

__device__ __forceinline__ float b2f(unsigned short u) {
    union { unsigned int i; float f; } v; v.i = ((unsigned int)u) << 16; return v.f;
}
__device__ __forceinline__ unsigned short f2b(float f) {
    union { float f; unsigned int i; } v; v.f = f;
    return (unsigned short)((v.i + 0x7FFFu + ((v.i >> 16) & 1u)) >> 16);  // RTNE
}
__device__ __forceinline__ float silu_f(float x) {
    return x / (1.0f + __expf(-x));
}
__device__ __forceinline__ f32x4 mfma16(bfrag8 a, bfrag8 b, f32x4 c) {
    return __builtin_amdgcn_mfma_f32_16x16x32_bf16(a, b, c, 0, 0, 0);
}

// ---- LDS layout (bytes) ----------------------------------------------------
// sL1  : 128 rows x 264 bf16 (4-rows-per-atom l1 tile, zero row every 4th) 67584
// sCtx : 32 x 520 bf16  [ l0 | vVn ]                                      33280
//        after P2a this region is reused:
//          sGate 32x264 bf16 (16896) | uP/wP 8x96 f32 (6144) | uSum/wSum
//          96 f32 each (768) | sVnb 32 f32 (128)
// sH   : 32 x 264 bf16 (h, later h_b)                                     16896
// sS1  : 32 x 264 bf16                                                    16896
// total 134656 B  (1 WG/CU on 160 KiB LDS)
#define OFF_CTX  67584
#define OFF_UP   (OFF_CTX + 16896)
#define OFF_WP   (OFF_UP + 3072)
#define OFF_USUM (OFF_WP + 3072)
#define OFF_WSUM (OFF_USUM + 384)
#define OFF_VNB  (OFF_WSUM + 384)
#define OFF_H    100864
#define OFF_S1   117760
#define SMEM_BYTES 134656

__global__ __launch_bounds__(512, 2) void dipole_fused(
    const float* __restrict__ pos,     // (N,3) f32
    const float* __restrict__ l0,      // (N,256) f32
    const float* __restrict__ l1,      // (N,3,256) f32
    const int*   __restrict__ batch,   // (N,)
    const float* __restrict__ b1a,     // (256,)
    const float* __restrict__ b2a,     // (512,)
    const float* __restrict__ wmix2,   // (256,2)
    const float* __restrict__ w1b,     // (257,256) original (row 256 used)
    const float* __restrict__ b1b,     // (256,)
    const float* __restrict__ w2b,     // (256,2)
    const float* __restrict__ b2b,     // (2,)
    const unsigned short* __restrict__ wt_mix1, // (512,256) bf16 Wmix1^T
    const unsigned short* __restrict__ wt_1a,   // (256,512) bf16 W1a^T
    const unsigned short* __restrict__ wt_2a,   // (512,256) bf16 W2a^T
    const unsigned short* __restrict__ wt_1b,   // (256,256) bf16 W1b[:256]^T
    float* __restrict__ out)           // [0:6144) y accum, [6144:12288) yv accum
{
    __shared__ __align__(16) char smem[SMEM_BYTES];
    unsigned short* sL1  = (unsigned short*)smem;               // pitch 264
    unsigned short* sCtx = (unsigned short*)(smem + OFF_CTX);   // pitch 520
    unsigned short* sGate= (unsigned short*)(smem + OFF_CTX);   // pitch 264 (alias, live after P2a)
    float* uP   = (float*)(smem + OFF_UP);                      // [8][96]
    float* wP   = (float*)(smem + OFF_WP);                      // [8][96]
    float* uSum = (float*)(smem + OFF_USUM);                    // [96]
    float* wSum = (float*)(smem + OFF_WSUM);                    // [96]
    float* sVnb = (float*)(smem + OFF_VNB);                     // [32]
    unsigned short* sH  = (unsigned short*)(smem + OFF_H);      // pitch 264
    unsigned short* sS1 = (unsigned short*)(smem + OFF_S1);     // pitch 264

    const int tid  = threadIdx.x;
    const int wv   = tid >> 6;
    const int lane = tid & 63;
    const int q    = lane >> 4;   // quad 0..3
    const int l15  = lane & 15;
    const int n0   = blockIdx.x * M_TILE;

    // ---- Stage: l1 -> sL1 (4-row-per-atom, f32->bf16), l0 -> sCtx[:, :256] -
    {
        // sL1: 128 rows x 64 chunks of 4 cols = 8192 chunks, 16 per thread
        #pragma unroll
        for (int p = 0; p < 16; ++p) {
            int idx = p * 512 + tid;
            int R = idx >> 6;              // 0..127
            int c4 = (idx & 63) * 4;       // 0..252
            int n = R >> 2, cc = R & 3;
            ushort4 o;
            if (cc < 3) {
                const float4 f = *(const float4*)&l1[((size_t)(n0 + n) * 3 + cc) * 256 + c4];
                o.x = f2b(f.x); o.y = f2b(f.y); o.z = f2b(f.z); o.w = f2b(f.w);
            } else {
                o.x = 0; o.y = 0; o.z = 0; o.w = 0;
            }
            *(ushort4*)&sL1[R * 264 + c4] = o;
        }
        // l0: 32 rows x 64 chunks = 2048 chunks, 4 per thread
        #pragma unroll
        for (int p = 0; p < 4; ++p) {
            int idx = p * 512 + tid;
            int r = idx >> 6, c4 = (idx & 63) * 4;
            const float4 f = *(const float4*)&l0[(size_t)(n0 + r) * 256 + c4];
            ushort4 o;
            o.x = f2b(f.x); o.y = f2b(f.y); o.z = f2b(f.z); o.w = f2b(f.w);
            *(ushort4*)&sCtx[r * 520 + c4] = o;
        }
    }
    __syncthreads();

    // ---- P1: vV = l1_tile @ Wmix1[:, :256]; vVn -> sCtx[:, 256:512] --------
    {
        const int o0 = wv * 32;
        bfrag8 bfr[2][8];
        #pragma unroll
        for (int ct = 0; ct < 2; ++ct) {
            const unsigned short* bp = wt_mix1 + (o0 + ct * 16 + l15) * 256 + q * 8;
            #pragma unroll
            for (int ks = 0; ks < 8; ++ks) bfr[ct][ks] = *(const bfrag8*)(bp + ks * 32);
        }
        #pragma unroll 2
        for (int rb = 0; rb < 8; ++rb) {
            f32x4 acc0 = {0.f, 0.f, 0.f, 0.f}, acc1 = {0.f, 0.f, 0.f, 0.f};
            const unsigned short* ap = &sL1[(rb * 16 + l15) * 264 + q * 8];
            #pragma unroll
            for (int ks = 0; ks < 8; ++ks) {
                bfrag8 af = *(const bfrag8*)(ap + ks * 32);
                acc0 = mfma16(af, bfr[0][ks], acc0);
                acc1 = mfma16(af, bfr[1][ks], acc1);
            }
            int n = rb * 4 + q;   // lane's atom; regs 0..2 = c components, reg 3 = zero row
            float s0 = acc0[0] * acc0[0] + acc0[1] * acc0[1] + acc0[2] * acc0[2];
            float s1 = acc1[0] * acc1[0] + acc1[1] * acc1[1] + acc1[2] * acc1[2];
            sCtx[n * 520 + 256 + o0 + l15]      = f2b(sqrtf(s0));
            sCtx[n * 520 + 256 + o0 + 16 + l15] = f2b(sqrtf(s1));
        }
    }
    __syncthreads();

    // ---- P2a: h = silu(ctx @ W1a + b1a) ------------------------------------
    {
        const int o0 = wv * 32;
        bfrag8 bfr[2][16];
        #pragma unroll
        for (int ct = 0; ct < 2; ++ct) {
            const unsigned short* bp = wt_1a + (o0 + ct * 16 + l15) * 512 + q * 8;
            #pragma unroll
            for (int ks = 0; ks < 16; ++ks) bfr[ct][ks] = *(const bfrag8*)(bp + ks * 32);
        }
        f32x4 acc[2][2] = {};
        const unsigned short* ap0 = &sCtx[l15 * 520 + q * 8];
        const unsigned short* ap1 = &sCtx[(16 + l15) * 520 + q * 8];
        #pragma unroll
        for (int ks = 0; ks < 16; ++ks) {
            bfrag8 a0 = *(const bfrag8*)(ap0 + ks * 32);
            bfrag8 a1 = *(const bfrag8*)(ap1 + ks * 32);
            acc[0][0] = mfma16(a0, bfr[0][ks], acc[0][0]);
            acc[0][1] = mfma16(a0, bfr[1][ks], acc[0][1]);
            acc[1][0] = mfma16(a1, bfr[0][ks], acc[1][0]);
            acc[1][1] = mfma16(a1, bfr[1][ks], acc[1][1]);
        }
        #pragma unroll
        for (int ct = 0; ct < 2; ++ct) {
            int o = o0 + ct * 16 + l15;
            float bias = b1a[o];
            #pragma unroll
            for (int rb = 0; rb < 2; ++rb)
                #pragma unroll
                for (int rg = 0; rg < 4; ++rg) {
                    int r = rb * 16 + q * 4 + rg;
                    sH[r * 264 + o] = f2b(silu_f(acc[rb][ct][rg] + bias));
                }
        }
    }
    __syncthreads();

    // ---- P2b: x = h @ W2a + b2a ; s1 = silu(x[:,:256]) ; gate = x[:,256:] --
    {
        #pragma unroll
        for (int cp = 0; cp < 2; ++cp) {
            const int o0 = wv * 64 + cp * 32;
            bfrag8 bfr[2][8];
            #pragma unroll
            for (int ct = 0; ct < 2; ++ct) {
                const unsigned short* bp = wt_2a + (o0 + ct * 16 + l15) * 256 + q * 8;
                #pragma unroll
                for (int ks = 0; ks < 8; ++ks) bfr[ct][ks] = *(const bfrag8*)(bp + ks * 32);
            }
            f32x4 acc[2][2] = {};
            const unsigned short* ap0 = &sH[l15 * 264 + q * 8];
            const unsigned short* ap1 = &sH[(16 + l15) * 264 + q * 8];
            #pragma unroll
            for (int ks = 0; ks < 8; ++ks) {
                bfrag8 a0 = *(const bfrag8*)(ap0 + ks * 32);
                bfrag8 a1 = *(const bfrag8*)(ap1 + ks * 32);
                acc[0][0] = mfma16(a0, bfr[0][ks], acc[0][0]);
                acc[0][1] = mfma16(a0, bfr[1][ks], acc[0][1]);
                acc[1][0] = mfma16(a1, bfr[0][ks], acc[1][0]);
                acc[1][1] = mfma16(a1, bfr[1][ks], acc[1][1]);
            }
            #pragma unroll
            for (int ct = 0; ct < 2; ++ct) {
                int o = o0 + ct * 16 + l15;
                float bias = b2a[o];
                #pragma unroll
                for (int rb = 0; rb < 2; ++rb)
                    #pragma unroll
                    for (int rg = 0; rg < 4; ++rg) {
                        int r = rb * 16 + q * 4 + rg;
                        float val = acc[rb][ct][rg] + bias;
                        if (o < 256) sS1[r * 264 + o] = f2b(silu_f(val));        // waves 0-3
                        else         sGate[r * 264 + (o - 256)] = f2b(val);      // waves 4-7
                    }
            }
        }
    }
    __syncthreads();

    // ---- P3: vW = l1_tile @ Wmix1[:, 256:], fused contraction:
    //          u[n,c] = sum_o vW*gate*Wmix2[o,0], w[n,c] likewise col 1 ------
    {
        const int o0 = wv * 32;
        bfrag8 bfr[2][8];
        float wm0[2], wm1[2];
        #pragma unroll
        for (int ct = 0; ct < 2; ++ct) {
            int og = o0 + ct * 16 + l15;                       // gate/vW col 0..255
            const unsigned short* bp = wt_mix1 + (256 + og) * 256 + q * 8;
            #pragma unroll
            for (int ks = 0; ks < 8; ++ks) bfr[ct][ks] = *(const bfrag8*)(bp + ks * 32);
            wm0[ct] = wmix2[og * 2];
            wm1[ct] = wmix2[og * 2 + 1];
        }
        #pragma unroll 2
        for (int rb = 0; rb < 8; ++rb) {
            f32x4 acc0 = {0.f, 0.f, 0.f, 0.f}, acc1 = {0.f, 0.f, 0.f, 0.f};
            const unsigned short* ap = &sL1[(rb * 16 + l15) * 264 + q * 8];
            #pragma unroll
            for (int ks = 0; ks < 8; ++ks) {
                bfrag8 af = *(const bfrag8*)(ap + ks * 32);
                acc0 = mfma16(af, bfr[0][ks], acc0);
                acc1 = mfma16(af, bfr[1][ks], acc1);
            }
            int n = rb * 4 + q;
            float ga0 = b2f(sGate[n * 264 + o0 + l15]);
            float ga1 = b2f(sGate[n * 264 + o0 + 16 + l15]);
            #pragma unroll
            for (int c = 0; c < 3; ++c) {
                float up = acc0[c] * ga0 * wm0[0] + acc1[c] * ga1 * wm0[1];
                float wp = acc0[c] * ga0 * wm1[0] + acc1[c] * ga1 * wm1[1];
                #pragma unroll
                for (int off = 1; off < 16; off <<= 1) {
                    up += __shfl_xor(up, off, 64);
                    wp += __shfl_xor(wp, off, 64);
                }
                if (l15 == 0) {   // one writer per (wave, n, c)
                    uP[wv * 96 + n * 3 + c] = up;
                    wP[wv * 96 + n * 3 + c] = wp;
                }
            }
        }
    }
    __syncthreads();

    // ---- reduce wave partials; vVn_b ---------------------------------------
    if (tid < 96) {
        float us = 0.f, ws = 0.f;
        #pragma unroll
        for (int w = 0; w < 8; ++w) { us += uP[w * 96 + tid]; ws += wP[w * 96 + tid]; }
        uSum[tid] = us; wSum[tid] = ws;
    }
    __syncthreads();
    if (tid < 32) {
        float a = uSum[tid * 3], b = uSum[tid * 3 + 1], c = uSum[tid * 3 + 2];
        sVnb[tid] = sqrtf(a * a + b * b + c * c);
    }
    __syncthreads();

    // ---- P4: h_b = silu(s1 @ W1b[:256] + b1b + vVn_b * W1b[256]) -----------
    {
        const int o0 = wv * 32;
        bfrag8 bfr[2][8];
        float bb[2], wl[2];
        #pragma unroll
        for (int ct = 0; ct < 2; ++ct) {
            int o = o0 + ct * 16 + l15;
            const unsigned short* bp = wt_1b + o * 256 + q * 8;
            #pragma unroll
            for (int ks = 0; ks < 8; ++ks) bfr[ct][ks] = *(const bfrag8*)(bp + ks * 32);
            bb[ct] = b1b[o];
            wl[ct] = w1b[256 * 256 + o];   // W1b row 256
        }
        f32x4 acc[2][2] = {};
        const unsigned short* ap0 = &sS1[l15 * 264 + q * 8];
        const unsigned short* ap1 = &sS1[(16 + l15) * 264 + q * 8];
        #pragma unroll
        for (int ks = 0; ks < 8; ++ks) {
            bfrag8 a0 = *(const bfrag8*)(ap0 + ks * 32);
            bfrag8 a1 = *(const bfrag8*)(ap1 + ks * 32);
            acc[0][0] = mfma16(a0, bfr[0][ks], acc[0][0]);
            acc[0][1] = mfma16(a0, bfr[1][ks], acc[0][1]);
            acc[1][0] = mfma16(a1, bfr[0][ks], acc[1][0]);
            acc[1][1] = mfma16(a1, bfr[1][ks], acc[1][1]);
        }
        #pragma unroll
        for (int ct = 0; ct < 2; ++ct) {
            int o = o0 + ct * 16 + l15;
            #pragma unroll
            for (int rb = 0; rb < 2; ++rb)
                #pragma unroll
                for (int rg = 0; rg < 4; ++rg) {
                    int r = rb * 16 + q * 4 + rg;
                    float val = acc[rb][ct][rg] + bb[ct] + sVnb[r] * wl[ct];
                    sH[r * 264 + o] = f2b(silu_f(val));   // h_b reuses sH
                }
        }
    }
    __syncthreads();

    // ---- P5: x_b = h_b @ W2b + b2b ; outputs + segment atomics -------------
    {
        const float b2b0 = b2b[0], b2b1 = b2b[1];
        #pragma unroll
        for (int j = 0; j < 4; ++j) {
            int a = wv * 4 + j;                  // atom within tile
            float qp = 0.f, gp = 0.f;
            #pragma unroll
            for (int t = 0; t < 4; ++t) {
                float h = b2f(sH[a * 264 + lane * 4 + t]);
                qp += h * w2b[(lane * 4 + t) * 2];
                gp += h * w2b[(lane * 4 + t) * 2 + 1];
            }
            #pragma unroll
            for (int off = 1; off < 64; off <<= 1) {
                qp += __shfl_xor(qp, off, 64);
                gp += __shfl_xor(gp, off, 64);
            }
            if (lane == 0) {
                float qv = qp + b2b0;            // charge
                float gv = gp + b2b1;            // gate_b
                int gA = n0 + a;
                int mol = batch[gA];
                #pragma unroll
                for (int c = 0; c < 3; ++c) {
                    float v2 = gv * wSum[a * 3 + c];
                    float yc = v2 + qv * pos[gA * 3 + c];
                    unsafeAtomicAdd(&out[mol * 3 + c], yc);          // y
                    unsafeAtomicAdd(&out[6144 + mol * 3 + c], v2);   // y_vector
                }
            }
        }
    }
}

// ---- setup: transpose weights (f32 -> bf16) into ws ------------------------
__global__ __launch_bounds__(256) void transpose_weights(
    const float* __restrict__ wmix1, const float* __restrict__ w1a,
    const float* __restrict__ w2a,   const float* __restrict__ w1b,
    unsigned short* __restrict__ wt_mix1, unsigned short* __restrict__ wt_1a,
    unsigned short* __restrict__ wt_2a,   unsigned short* __restrict__ wt_1b)
{
    int id = blockIdx.x * 256 + threadIdx.x;
    if (id < 131072) {                       // Wmix1 (256,512) -> (512,256)
        int o = id >> 8, i = id & 255;
        wt_mix1[id] = f2b(wmix1[i * 512 + o]);
    } else if (id < 262144) {                // W1a (512,256) -> (256,512)
        int t = id - 131072; int o = t >> 9, k = t & 511;
        wt_1a[t] = f2b(w1a[k * 256 + o]);
    } else if (id < 393216) {                // W2a (256,512) -> (512,256)
        int t = id - 262144; int o = t >> 8, k = t & 255;
        wt_2a[t] = f2b(w2a[k * 512 + o]);
    } else if (id < 458752) {                // W1b[:256] (256,256) -> (256,256)
        int t = id - 393216; int o = t >> 8, k = t & 255;
        wt_1b[t] = f2b(w1b[k * 256 + o]);
    }
}

extern "C" void kernel_launch(void* const* d_in, const int* in_sizes, int n_in,
                              void* d_out, int out_size, void* d_ws, size_t ws_size,
                              hipStream_t stream) {
    const float* pos   = (const float*)d_in[0];
    const float* l0    = (const float*)d_in[1];
    const float* l1    = (const float*)d_in[2];
    const int*   batch = (const int*)d_in[3];
    const float* wmix1 = (const float*)d_in[4];
    const float* w1a   = (const float*)d_in[5];
    const float* b1a   = (const float*)d_in[6];
    const float* w2a   = (const float*)d_in[7];
    const float* b2a   = (const float*)d_in[8];
    const float* wmix2 = (const float*)d_in[9];
    const float* w1b   = (const float*)d_in[10];
    const float* b1b   = (const float*)d_in[11];
    const float* w2b   = (const float*)d_in[12];
    const float* b2b   = (const float*)d_in[13];

    unsigned short* wt_mix1 = (unsigned short*)d_ws;             // 512x256 bf16
    unsigned short* wt_1a   = wt_mix1 + 131072;                  // 256x512
    unsigned short* wt_2a   = wt_1a + 131072;                    // 512x256
    unsigned short* wt_1b   = wt_2a + 131072;                    // 256x256
    // total ws use: 458752 * 2 B = 896 KiB

    // d_out is poisoned 0xAA before every timed replay -> zero it (we
    // accumulate the segment sums directly into it with f32 atomics).
    hipMemsetAsync(d_out, 0, (size_t)out_size * sizeof(float), stream);
    transpose_weights<<<1792, 256, 0, stream>>>(wmix1, w1a, w2a, w1b,
                                                wt_mix1, wt_1a, wt_2a, wt_1b);
    dipole_fused<<<NWG, 512, 0, stream>>>(pos, l0, l1, batch, b1a, b2a, wmix2,
                                          w1b, b1b, w2b, b2b,
                                          wt_mix1, wt_1a, wt_2a, wt_1b,
                                          (float*)d_out);
}